// Round 1
// 598.123 us; speedup vs baseline: 1.0263x; 1.0263x over previous
//
#include <hip/hip_runtime.h>
#include <stdint.h>

// Problem constants (fixed by setup_inputs shapes)
#define B_   32
#define C_   192
#define Hh   64
#define Ww   64
#define LS   256    // 16*16 pooled positions
#define DI   384    // d_inner
#define DSt  16     // d_state
#define E2   768    // 2*d_inner

// ---------------------------------------------------------------------------
// K1: 4x4 avg-pool + LayerNorm over C=192. One block per (b, pooled pos).
// ---------------------------------------------------------------------------
__global__ __launch_bounds__(192) void k_pool_ln(
    const float* __restrict__ x, const float* __restrict__ w, const float* __restrict__ bb,
    float* __restrict__ xln)
{
  int row = blockIdx.x;            // b*256 + ls
  int b = row >> 8, ls = row & 255;
  int i = ls >> 4, j = ls & 15;
  int c = threadIdx.x;
  const float* xp = x + (((size_t)(b * C_ + c) * Hh + i * 4) * Ww + j * 4);
  float s = 0.f;
#pragma unroll
  for (int r = 0; r < 4; ++r) {
    float4 v = *reinterpret_cast<const float4*>(xp + (size_t)r * Ww);
    s += v.x + v.y + v.z + v.w;
  }
  float pooled = s * (1.f / 16.f);
  float s1 = pooled, s2 = pooled * pooled;
#pragma unroll
  for (int off = 32; off; off >>= 1) {
    s1 += __shfl_xor(s1, off, 64);
    s2 += __shfl_xor(s2, off, 64);
  }
  __shared__ float a1[3], a2[3], mv[2];
  int wid = c >> 6;
  if ((c & 63) == 0) { a1[wid] = s1; a2[wid] = s2; }
  __syncthreads();
  if (c == 0) {
    float t1 = a1[0] + a1[1] + a1[2], t2 = a2[0] + a2[1] + a2[2];
    float mu = t1 / 192.f;
    float var = t2 / 192.f - mu * mu;
    mv[0] = mu; mv[1] = rsqrtf(var + 1e-5f);
  }
  __syncthreads();
  float val = (pooled - mv[0]) * mv[1] * w[c] + bb[c];
  xln[(size_t)row * C_ + c] = val;
}

// ---------------------------------------------------------------------------
// K2/K7: f32 NT GEMM. C[m,n] = sum_k A[m,k]*W[n,k].
// 128x128 block tile, BK=8, 256 threads, 8x8 register tile per thread.
// ---------------------------------------------------------------------------
__global__ __launch_bounds__(256) void k_gemm_f32(
    const float* __restrict__ A, const float* __restrict__ W,
    float* __restrict__ C, int N, int K)
{
  __shared__ float At[8][132];
  __shared__ float Wt[8][132];
  int tid = threadIdx.x;
  int m0 = blockIdx.y * 128, n0 = blockIdx.x * 128;
  int tx = tid & 15, ty = tid >> 4;
  int lr = tid >> 1, lk = (tid & 1) * 4;
  float acc[8][8] = {};
  const float* Arow = A + (size_t)(m0 + lr) * K + lk;
  int wrow = n0 + lr; if (wrow >= N) wrow = N - 1;
  const float* Wrow = W + (size_t)wrow * K + lk;
  for (int k0 = 0; k0 < K; k0 += 8) {
    float4 av = *reinterpret_cast<const float4*>(Arow + k0);
    float4 wv = *reinterpret_cast<const float4*>(Wrow + k0);
    __syncthreads();
    At[lk + 0][lr] = av.x; At[lk + 1][lr] = av.y; At[lk + 2][lr] = av.z; At[lk + 3][lr] = av.w;
    Wt[lk + 0][lr] = wv.x; Wt[lk + 1][lr] = wv.y; Wt[lk + 2][lr] = wv.z; Wt[lk + 3][lr] = wv.w;
    __syncthreads();
#pragma unroll
    for (int k = 0; k < 8; ++k) {
      float4 a0 = *reinterpret_cast<const float4*>(&At[k][8 * ty]);
      float4 a1 = *reinterpret_cast<const float4*>(&At[k][8 * ty + 4]);
      float4 w0 = *reinterpret_cast<const float4*>(&Wt[k][8 * tx]);
      float4 w1 = *reinterpret_cast<const float4*>(&Wt[k][8 * tx + 4]);
      float a[8] = {a0.x, a0.y, a0.z, a0.w, a1.x, a1.y, a1.z, a1.w};
      float w[8] = {w0.x, w0.y, w0.z, w0.w, w1.x, w1.y, w1.z, w1.w};
#pragma unroll
      for (int i = 0; i < 8; ++i)
#pragma unroll
        for (int j = 0; j < 8; ++j) acc[i][j] += a[i] * w[j];
    }
  }
#pragma unroll
  for (int i = 0; i < 8; ++i) {
    int row = m0 + 8 * ty + i;
    int col0 = n0 + 8 * tx;
    if (col0 < N)
      *reinterpret_cast<float4*>(C + (size_t)row * N + col0) =
          make_float4(acc[i][0], acc[i][1], acc[i][2], acc[i][3]);
    if (col0 + 4 < N)
      *reinterpret_cast<float4*>(C + (size_t)row * N + col0 + 4) =
          make_float4(acc[i][4], acc[i][5], acc[i][6], acc[i][7]);
  }
}

// ---------------------------------------------------------------------------
// K3: depthwise conv1d (k=3, zero pad) over seq + SiLU. One thread per (b,l,e).
// ---------------------------------------------------------------------------
__global__ __launch_bounds__(256) void k_conv_silu(
    const float* __restrict__ xz, const float* __restrict__ cw, const float* __restrict__ cb,
    float* __restrict__ xc)
{
  int idx = blockIdx.x * 256 + threadIdx.x;   // (b*256+l)*384 + e
  int e = idx % DI;
  int row = idx / DI;
  int l = row & 255;
  const float* xin = xz + (size_t)row * E2 + e;
  float x0 = *xin;
  float xm = (l > 0)   ? *(xin - E2) : 0.f;
  float xp = (l < 255) ? *(xin + E2) : 0.f;
  float v = cw[e * 3 + 0] * xm + cw[e * 3 + 1] * x0 + cw[e * 3 + 2] * xp + cb[e];
  xc[idx] = v / (1.f + expf(-v));
}

// ---------------------------------------------------------------------------
// K4: x_proj (33 dots of len 384) + dt_proj + softplus. One wave per (b,l) row.
// ---------------------------------------------------------------------------
__global__ __launch_bounds__(256) void k_xproj(
    const float* __restrict__ xc, const float* __restrict__ xw,
    const float* __restrict__ dtw, const float* __restrict__ dtb,
    float* __restrict__ BC, float* __restrict__ delta)
{
  int wid = threadIdx.x >> 6, lane = threadIdx.x & 63;
  int row = blockIdx.x * 4 + wid;
  const float* xr = xc + (size_t)row * DI;
  float xv[6];
#pragma unroll
  for (int k = 0; k < 6; ++k) xv[k] = xr[lane + 64 * k];
  float dres = 0.f, mine = 0.f;
  for (int j = 0; j < 33; ++j) {
    const float* wr = xw + (size_t)j * DI;
    float p = 0.f;
#pragma unroll
    for (int k = 0; k < 6; ++k) p += wr[lane + 64 * k] * xv[k];
#pragma unroll
    for (int off = 32; off; off >>= 1) p += __shfl_xor(p, off, 64);
    if (j == 0) dres = p;
    else if (lane == j - 1) mine = p;
  }
  if (lane < 32) BC[(size_t)row * 32 + lane] = mine;   // [0..15]=B_mat, [16..31]=C_mat
#pragma unroll
  for (int k = 0; k < 6; ++k) {
    int e = lane + 64 * k;
    float dr = dres * dtw[e] + dtb[e];
    delta[(size_t)row * DI + e] = dr > 20.f ? dr : log1pf(expf(dr));
  }
}

// ---------------------------------------------------------------------------
// K5: selective scan, cache-line-coherent version.
// Block = (b, group of 16 consecutive e); 256 threads = 16 et x 16 s,
// tid = et*16 + s. Each thread runs the plain serial 256-step recurrence
// for its (e, s) — no chunk/replay arrays (the old version spilled 64
// floats/thread to scratch: VGPR_Count=48 < 64-float arrays; WRITE_SIZE
// 98 MB vs 12.6 MB ideal). Per step the block consumes full 64 B lines of
// delta/xc/z and the 128 B BC row, so FETCH is the algorithmic minimum.
// s-reduction y = sum_s h*C via 4-level shfl_xor within each 16-lane group.
// 768 blocks x 4 waves = 12 waves/CU hides the serial FMA chain.
// ---------------------------------------------------------------------------
__global__ __launch_bounds__(256) void k_scan(
    const float* __restrict__ delta, const float* __restrict__ xc,
    const float* __restrict__ BC, const float* __restrict__ xz,
    const float* __restrict__ A_log, const float* __restrict__ Dp,
    float* __restrict__ yg)
{
  int blk = blockIdx.x;            // b*24 + eg
  int b = blk / 24, eg = blk - b * 24;
  int tid = threadIdx.x;
  int et = tid >> 4, s = tid & 15;
  int e = eg * 16 + et;
  float Aes = -expf(A_log[e * DSt + s]);
  float Dv = Dp[e];
  size_t rbase = (size_t)b * 256;
  const float* pd = delta + rbase * DI + e;
  const float* px = xc + rbase * DI + e;
  const float* pb = BC + rbase * 32 + s;
  const float* pz = xz + rbase * E2 + DI + e;
  float* py = yg + rbase * DI + e;

  // 1-step load rotation so next step's loads issue under current compute.
  float dv = pd[0], xcv = px[0], Bm = pb[0], Cm = pb[16], zv = pz[0];
  float h = 0.f;
#pragma unroll 4
  for (int l = 0; l < 256; ++l) {
    float dv_n = 0.f, xcv_n = 0.f, Bm_n = 0.f, Cm_n = 0.f, zv_n = 0.f;
    if (l < 255) {
      size_t r = (size_t)(l + 1);
      dv_n  = pd[r * DI];
      xcv_n = px[r * DI];
      Bm_n  = pb[r * 32];
      Cm_n  = pb[r * 32 + 16];
      zv_n  = pz[r * E2];
    }
    float da = expf(dv * Aes);
    h = da * h + dv * Bm * xcv;
    float contrib = h * Cm;
    contrib += __shfl_xor(contrib, 1, 64);
    contrib += __shfl_xor(contrib, 2, 64);
    contrib += __shfl_xor(contrib, 4, 64);
    contrib += __shfl_xor(contrib, 8, 64);
    if (s == 0) {
      float y = (contrib + xcv * Dv) * (zv / (1.f + expf(-zv)));
      py[(size_t)l * DI] = y;
    }
    dv = dv_n; xcv = xcv_n; Bm = Bm_n; Cm = Cm_n; zv = zv_n;
  }
}

// ---------------------------------------------------------------------------
// K6: LayerNorm over d_inner=384, f32 out.
// ---------------------------------------------------------------------------
__global__ __launch_bounds__(128) void k_ln_ssm(
    const float* __restrict__ yg, const float* __restrict__ nw, const float* __restrict__ nb,
    float* __restrict__ yn)
{
  int row = blockIdx.x;
  int t = threadIdx.x;
  const float* yr = yg + (size_t)row * DI;
  float v0 = yr[t], v1 = yr[t + 128], v2 = yr[t + 256];
  float s1 = v0 + v1 + v2, s2 = v0 * v0 + v1 * v1 + v2 * v2;
#pragma unroll
  for (int off = 32; off; off >>= 1) {
    s1 += __shfl_xor(s1, off, 64);
    s2 += __shfl_xor(s2, off, 64);
  }
  __shared__ float a1[2], a2[2];
  if ((t & 63) == 0) { a1[t >> 6] = s1; a2[t >> 6] = s2; }
  __syncthreads();
  float t1 = a1[0] + a1[1], t2 = a2[0] + a2[1];
  float mu = t1 / 384.f, var = t2 / 384.f - mu * mu;
  float rstd = rsqrtf(var + 1e-5f);
  float* yo = yn + (size_t)row * DI;
  yo[t]       = (v0 - mu) * rstd * nw[t]       + nb[t];
  yo[t + 128] = (v1 - mu) * rstd * nw[t + 128] + nb[t + 128];
  yo[t + 256] = (v2 - mu) * rstd * nw[t + 256] + nb[t + 256];
}

// ---------------------------------------------------------------------------
// K8: fused 7x7 depthwise conv + bilinear 4x upsample of ssm + gated combine.
// ---------------------------------------------------------------------------
__global__ __launch_bounds__(256) void k_final(
    const float* __restrict__ x, const float* __restrict__ dww, const float* __restrict__ dwb,
    const float* __restrict__ ssm, const float* __restrict__ gate,
    float* __restrict__ out)
{
  int blk = blockIdx.x;
  int ti = blk & 3;
  int c = (blk >> 2) % C_;
  int b = blk / (4 * C_);
  int h0 = ti * 16;
  __shared__ float xpatch[22 * 72];
  __shared__ float wlds[49];
  __shared__ float slds[6 * 16];
  __shared__ float biass;
  int tid = threadIdx.x;
  if (tid < 49) wlds[tid] = dww[(size_t)c * 49 + tid];
  if (tid == 49) biass = dwb[c];
  int ibase = (h0 >> 2) - 1;   // floor(h0*0.25 - 0.375)
  if (tid < 96) {
    int ii = ibase + (tid >> 4);
    ii = ii < 0 ? 0 : (ii > 15 ? 15 : ii);
    int jj = tid & 15;
    slds[tid] = ssm[((size_t)(b * LS) + ii * 16 + jj) * C_ + c];
  }
  const float* xb = x + ((size_t)(b * C_ + c) * Hh) * Ww;
  for (int idx = tid; idx < 22 * 70; idx += 256) {
    int r = idx / 70, col = idx % 70;
    int gh = h0 - 3 + r, gw = col - 3;
    float v = 0.f;
    if (gh >= 0 && gh < 64 && gw >= 0 && gw < 64)
      v = xb[gh * 64 + gw];
    xpatch[r * 72 + col] = v;
  }
  __syncthreads();
  float g = 1.f / (1.f + expf(-gate[0]));
  int qn = tid >> 5;             // 0..7
  int R0 = qn * 2;
  int w0 = (tid & 31) * 2;
  float a00 = 0, a01 = 0, a10 = 0, a11 = 0;
#pragma unroll
  for (int k = 0; k < 8; ++k) {
    const float* prow = &xpatch[(R0 + k) * 72 + w0];
    float v[8];
#pragma unroll
    for (int d = 0; d < 8; ++d) v[d] = prow[d];
    if (k < 7) {
#pragma unroll
      for (int dx = 0; dx < 7; ++dx) {
        float wv = wlds[k * 7 + dx];
        a00 += wv * v[dx]; a01 += wv * v[dx + 1];
      }
    }
    if (k > 0) {
#pragma unroll
      for (int dx = 0; dx < 7; ++dx) {
        float wv = wlds[(k - 1) * 7 + dx];
        a10 += wv * v[dx]; a11 += wv * v[dx + 1];
      }
    }
  }
  float locs[2][2] = {{a00 + biass, a01 + biass}, {a10 + biass, a11 + biass}};
  float* orow = out + ((size_t)(b * C_ + c) * Hh) * Ww;
#pragma unroll
  for (int rr = 0; rr < 2; ++rr) {
    int hgl = h0 + R0 + rr;
    float ci = hgl * 0.25f - 0.375f;
    float fif = floorf(ci);
    int i0 = (int)fif;
    float fi = ci - fif;
    int li = i0 - ibase;
    const float* r0p = &slds[li * 16];
    const float* r1p = &slds[(li + 1) * 16];
    float ov[2];
#pragma unroll
    for (int ccx = 0; ccx < 2; ++ccx) {
      int wgl = w0 + ccx;
      float cj = wgl * 0.25f - 0.375f;
      float fjf = floorf(cj);
      int j0 = (int)fjf;
      float fj = cj - fjf;
      int jc0 = j0 < 0 ? 0 : j0;
      int jc1 = (j0 + 1) > 15 ? 15 : (j0 + 1);
      float sv = (1.f - fi) * ((1.f - fj) * r0p[jc0] + fj * r0p[jc1])
               +         fi * ((1.f - fj) * r1p[jc0] + fj * r1p[jc1]);
      float xv = xpatch[(R0 + rr + 3) * 72 + (wgl + 3)];
      ov[ccx] = xv + g * sv + (1.f - g) * locs[rr][ccx];
    }
    *reinterpret_cast<float2*>(&orow[hgl * 64 + w0]) = make_float2(ov[0], ov[1]);
  }
}

// ---------------------------------------------------------------------------
extern "C" void kernel_launch(void* const* d_in, const int* in_sizes, int n_in,
                              void* d_out, int out_size, void* d_ws, size_t ws_size,
                              hipStream_t stream)
{
  const float* x    = (const float*)d_in[0];
  const float* inw  = (const float*)d_in[1];
  const float* xw   = (const float*)d_in[2];
  const float* dtw  = (const float*)d_in[3];
  const float* dtb  = (const float*)d_in[4];
  const float* cw   = (const float*)d_in[5];
  const float* cb   = (const float*)d_in[6];
  const float* alog = (const float*)d_in[7];
  const float* Dp   = (const float*)d_in[8];
  const float* ow   = (const float*)d_in[9];
  const float* nsw  = (const float*)d_in[10];
  const float* nsb  = (const float*)d_in[11];
  const float* n1w  = (const float*)d_in[12];
  const float* n1b  = (const float*)d_in[13];
  const float* dww  = (const float*)d_in[14];
  const float* dwb  = (const float*)d_in[15];
  const float* gate = (const float*)d_in[16];

  char* ws = (char*)d_ws;
  float* xln   = (float*)ws; ws += (size_t)8192 * 192 * 4;   // 6.3 MB
  float* xz    = (float*)ws; ws += (size_t)8192 * 768 * 4;   // 25.2 MB
  float* xc    = (float*)ws; ws += (size_t)8192 * 384 * 4;   // 12.6 MB
  float* delta = (float*)ws; ws += (size_t)8192 * 384 * 4;   // 12.6 MB
  float* BC    = (float*)ws; ws += (size_t)8192 * 32 * 4;    // 1.05 MB
  float* yg    = (float*)ws; ws += (size_t)8192 * 384 * 4;   // 12.6 MB
  float* yn  = xz;    // alias: xz dead after k_scan
  float* ssm = xln;   // alias: xln dead after gemm1

  k_pool_ln<<<8192, 192, 0, stream>>>(x, n1w, n1b, xln);
  k_gemm_f32<<<dim3(6, 64), 256, 0, stream>>>(xln, inw, xz, 768, 192);
  k_conv_silu<<<12288, 256, 0, stream>>>(xz, cw, cb, xc);
  k_xproj<<<2048, 256, 0, stream>>>(xc, xw, dtw, dtb, BC, delta);
  k_scan<<<B_ * 24, 256, 0, stream>>>(delta, xc, BC, xz, alog, Dp, yg);
  k_ln_ssm<<<8192, 128, 0, stream>>>(yg, nsw, nsb, yn);
  k_gemm_f32<<<dim3(2, 64), 256, 0, stream>>>(yn, ow, ssm, 192, 384);
  k_final<<<24576, 256, 0, stream>>>(x, dww, dwb, ssm, gate, (float*)d_out);
}

// Round 2
// 522.960 us; speedup vs baseline: 1.1738x; 1.1437x over previous
//
#include <hip/hip_runtime.h>
#include <stdint.h>

// Problem constants (fixed by setup_inputs shapes)
#define B_   32
#define C_   192
#define Hh   64
#define Ww   64
#define LS   256    // 16*16 pooled positions
#define DI   384    // d_inner
#define DSt  16     // d_state
#define E2   768    // 2*d_inner

// ---------------------------------------------------------------------------
// K1 v2: 4x4 avg-pool + LayerNorm over C=192, coalesced.
// Old version: block=(b,ls), thread=c -> consecutive lanes 16KB apart, 4x
// cache-line over-fetch (FETCH 393MB vs 101MB input, VALUBusy 2.8%).
// New: block=(b, pooled-row i), 256 threads. Per channel, the pool source
// region x[b,c,4i..4i+3,:] is 1024 contiguous bytes = 64 float4s = exactly
// one wave-wide coalesced load. 4 channels/iter (one per wave), 48 iters.
// Pool-reduce over the 4 rows via shfl_xor(16/32); LN stats over c via
// shfl + LDS tree; coalesced xln writes (consecutive tid -> consecutive c).
// ---------------------------------------------------------------------------
__global__ __launch_bounds__(256) void k_pool_ln(
    const float* __restrict__ x, const float* __restrict__ w, const float* __restrict__ bb,
    float* __restrict__ xln)
{
  int b = blockIdx.x >> 4, i = blockIdx.x & 15;
  int tid = threadIdx.x;
  int wv = tid >> 6;          // wave id 0..3 -> channel sub-index
  int off = tid & 63;         // float4 slot within the 4x64 region
  int j = off & 15;           // pooled col

  __shared__ float pooledT[16 * 193];   // [j][c], pitch 193 -> conflict-free
  __shared__ float red1[4][16], red2[4][16];
  __shared__ float muL[16], rsL[16];

  const float* xbase = x + (((size_t)(b * C_) * Hh + i * 4) * Ww);
#pragma unroll 4
  for (int cc = 0; cc < 48; ++cc) {
    int c = cc * 4 + wv;
    float4 v = *reinterpret_cast<const float4*>(xbase + (size_t)c * (Hh * Ww) + off * 4);
    float s = v.x + v.y + v.z + v.w;
    s += __shfl_xor(s, 16, 64);   // sum over row r (bits 4..5 of off)
    s += __shfl_xor(s, 32, 64);
    if (off < 16) pooledT[j * 193 + c] = s * (1.f / 16.f);
  }
  __syncthreads();

  // LN stats over c for each of the 16 pooled cols j.
  int j2 = tid & 15, cg = tid >> 4;   // cg 0..15, each sums 12 channels
  float s1 = 0.f, s2 = 0.f;
#pragma unroll
  for (int ccx = 0; ccx < 12; ++ccx) {
    float v = pooledT[j2 * 193 + cg * 12 + ccx];
    s1 += v; s2 += v * v;
  }
  // within-wave: lanes j2 + 16*{0..3} share j2 -> xor over bits 4..5
  s1 += __shfl_xor(s1, 16, 64); s1 += __shfl_xor(s1, 32, 64);
  s2 += __shfl_xor(s2, 16, 64); s2 += __shfl_xor(s2, 32, 64);
  if ((tid & 63) < 16) { red1[tid >> 6][j2] = s1; red2[tid >> 6][j2] = s2; }
  __syncthreads();
  if (tid < 16) {
    float t1 = red1[0][tid] + red1[1][tid] + red1[2][tid] + red1[3][tid];
    float t2 = red2[0][tid] + red2[1][tid] + red2[2][tid] + red2[3][tid];
    float mu = t1 / 192.f;
    float var = t2 / 192.f - mu * mu;
    muL[tid] = mu; rsL[tid] = rsqrtf(var + 1e-5f);
  }
  __syncthreads();

  // Write xln[(b*256 + i*16 + jj)*192 + c], coalesced in c.
#pragma unroll
  for (int k = 0; k < 12; ++k) {
    int o = tid + 256 * k;          // 0..3071
    int c = o % 192, jj = o / 192;
    float v = (pooledT[jj * 193 + c] - muL[jj]) * rsL[jj] * w[c] + bb[c];
    xln[((size_t)(b * 256 + i * 16 + jj)) * C_ + c] = v;
  }
}

// ---------------------------------------------------------------------------
// K2/K7: f32 NT GEMM. C[m,n] = sum_k A[m,k]*W[n,k].
// 128x128 block tile, BK=8, 256 threads, 8x8 register tile per thread.
// ---------------------------------------------------------------------------
__global__ __launch_bounds__(256) void k_gemm_f32(
    const float* __restrict__ A, const float* __restrict__ W,
    float* __restrict__ C, int N, int K)
{
  __shared__ float At[8][132];
  __shared__ float Wt[8][132];
  int tid = threadIdx.x;
  int m0 = blockIdx.y * 128, n0 = blockIdx.x * 128;
  int tx = tid & 15, ty = tid >> 4;
  int lr = tid >> 1, lk = (tid & 1) * 4;
  float acc[8][8] = {};
  const float* Arow = A + (size_t)(m0 + lr) * K + lk;
  int wrow = n0 + lr; if (wrow >= N) wrow = N - 1;
  const float* Wrow = W + (size_t)wrow * K + lk;
  for (int k0 = 0; k0 < K; k0 += 8) {
    float4 av = *reinterpret_cast<const float4*>(Arow + k0);
    float4 wv = *reinterpret_cast<const float4*>(Wrow + k0);
    __syncthreads();
    At[lk + 0][lr] = av.x; At[lk + 1][lr] = av.y; At[lk + 2][lr] = av.z; At[lk + 3][lr] = av.w;
    Wt[lk + 0][lr] = wv.x; Wt[lk + 1][lr] = wv.y; Wt[lk + 2][lr] = wv.z; Wt[lk + 3][lr] = wv.w;
    __syncthreads();
#pragma unroll
    for (int k = 0; k < 8; ++k) {
      float4 a0 = *reinterpret_cast<const float4*>(&At[k][8 * ty]);
      float4 a1 = *reinterpret_cast<const float4*>(&At[k][8 * ty + 4]);
      float4 w0 = *reinterpret_cast<const float4*>(&Wt[k][8 * tx]);
      float4 w1 = *reinterpret_cast<const float4*>(&Wt[k][8 * tx + 4]);
      float a[8] = {a0.x, a0.y, a0.z, a0.w, a1.x, a1.y, a1.z, a1.w};
      float w[8] = {w0.x, w0.y, w0.z, w0.w, w1.x, w1.y, w1.z, w1.w};
#pragma unroll
      for (int i = 0; i < 8; ++i)
#pragma unroll
        for (int j = 0; j < 8; ++j) acc[i][j] += a[i] * w[j];
    }
  }
#pragma unroll
  for (int i = 0; i < 8; ++i) {
    int row = m0 + 8 * ty + i;
    int col0 = n0 + 8 * tx;
    if (col0 < N)
      *reinterpret_cast<float4*>(C + (size_t)row * N + col0) =
          make_float4(acc[i][0], acc[i][1], acc[i][2], acc[i][3]);
    if (col0 + 4 < N)
      *reinterpret_cast<float4*>(C + (size_t)row * N + col0 + 4) =
          make_float4(acc[i][4], acc[i][5], acc[i][6], acc[i][7]);
  }
}

// ---------------------------------------------------------------------------
// K3: depthwise conv1d (k=3, zero pad) over seq + SiLU. One thread per (b,l,e).
// ---------------------------------------------------------------------------
__global__ __launch_bounds__(256) void k_conv_silu(
    const float* __restrict__ xz, const float* __restrict__ cw, const float* __restrict__ cb,
    float* __restrict__ xc)
{
  int idx = blockIdx.x * 256 + threadIdx.x;   // (b*256+l)*384 + e
  int e = idx % DI;
  int row = idx / DI;
  int l = row & 255;
  const float* xin = xz + (size_t)row * E2 + e;
  float x0 = *xin;
  float xm = (l > 0)   ? *(xin - E2) : 0.f;
  float xp = (l < 255) ? *(xin + E2) : 0.f;
  float v = cw[e * 3 + 0] * xm + cw[e * 3 + 1] * x0 + cw[e * 3 + 2] * xp + cb[e];
  xc[idx] = v / (1.f + expf(-v));
}

// ---------------------------------------------------------------------------
// K4: x_proj (33 dots of len 384) + dt_proj + softplus. One wave per (b,l) row.
// ---------------------------------------------------------------------------
__global__ __launch_bounds__(256) void k_xproj(
    const float* __restrict__ xc, const float* __restrict__ xw,
    const float* __restrict__ dtw, const float* __restrict__ dtb,
    float* __restrict__ BC, float* __restrict__ delta)
{
  int wid = threadIdx.x >> 6, lane = threadIdx.x & 63;
  int row = blockIdx.x * 4 + wid;
  const float* xr = xc + (size_t)row * DI;
  float xv[6];
#pragma unroll
  for (int k = 0; k < 6; ++k) xv[k] = xr[lane + 64 * k];
  float dres = 0.f, mine = 0.f;
  for (int j = 0; j < 33; ++j) {
    const float* wr = xw + (size_t)j * DI;
    float p = 0.f;
#pragma unroll
    for (int k = 0; k < 6; ++k) p += wr[lane + 64 * k] * xv[k];
#pragma unroll
    for (int off = 32; off; off >>= 1) p += __shfl_xor(p, off, 64);
    if (j == 0) dres = p;
    else if (lane == j - 1) mine = p;
  }
  if (lane < 32) BC[(size_t)row * 32 + lane] = mine;   // [0..15]=B_mat, [16..31]=C_mat
#pragma unroll
  for (int k = 0; k < 6; ++k) {
    int e = lane + 64 * k;
    float dr = dres * dtw[e] + dtb[e];
    delta[(size_t)row * DI + e] = dr > 20.f ? dr : log1pf(expf(dr));
  }
}

// ---------------------------------------------------------------------------
// K5: selective scan, cache-line-coherent version.
// Block = (b, group of 16 consecutive e); 256 threads = 16 et x 16 s,
// tid = et*16 + s. Each thread runs the plain serial 256-step recurrence
// for its (e, s) — no chunk/replay arrays. Per step the block consumes
// full 64 B lines of delta/xc/z and the 128 B BC row. s-reduction
// y = sum_s h*C via 4-level shfl_xor within each 16-lane group.
// ---------------------------------------------------------------------------
__global__ __launch_bounds__(256) void k_scan(
    const float* __restrict__ delta, const float* __restrict__ xc,
    const float* __restrict__ BC, const float* __restrict__ xz,
    const float* __restrict__ A_log, const float* __restrict__ Dp,
    float* __restrict__ yg)
{
  int blk = blockIdx.x;            // b*24 + eg
  int b = blk / 24, eg = blk - b * 24;
  int tid = threadIdx.x;
  int et = tid >> 4, s = tid & 15;
  int e = eg * 16 + et;
  float Aes = -expf(A_log[e * DSt + s]);
  float Dv = Dp[e];
  size_t rbase = (size_t)b * 256;
  const float* pd = delta + rbase * DI + e;
  const float* px = xc + rbase * DI + e;
  const float* pb = BC + rbase * 32 + s;
  const float* pz = xz + rbase * E2 + DI + e;
  float* py = yg + rbase * DI + e;

  // 1-step load rotation so next step's loads issue under current compute.
  float dv = pd[0], xcv = px[0], Bm = pb[0], Cm = pb[16], zv = pz[0];
  float h = 0.f;
#pragma unroll 4
  for (int l = 0; l < 256; ++l) {
    float dv_n = 0.f, xcv_n = 0.f, Bm_n = 0.f, Cm_n = 0.f, zv_n = 0.f;
    if (l < 255) {
      size_t r = (size_t)(l + 1);
      dv_n  = pd[r * DI];
      xcv_n = px[r * DI];
      Bm_n  = pb[r * 32];
      Cm_n  = pb[r * 32 + 16];
      zv_n  = pz[r * E2];
    }
    float da = expf(dv * Aes);
    h = da * h + dv * Bm * xcv;
    float contrib = h * Cm;
    contrib += __shfl_xor(contrib, 1, 64);
    contrib += __shfl_xor(contrib, 2, 64);
    contrib += __shfl_xor(contrib, 4, 64);
    contrib += __shfl_xor(contrib, 8, 64);
    if (s == 0) {
      float y = (contrib + xcv * Dv) * (zv / (1.f + expf(-zv)));
      py[(size_t)l * DI] = y;
    }
    dv = dv_n; xcv = xcv_n; Bm = Bm_n; Cm = Cm_n; zv = zv_n;
  }
}

// ---------------------------------------------------------------------------
// K6: LayerNorm over d_inner=384, f32 out.
// ---------------------------------------------------------------------------
__global__ __launch_bounds__(128) void k_ln_ssm(
    const float* __restrict__ yg, const float* __restrict__ nw, const float* __restrict__ nb,
    float* __restrict__ yn)
{
  int row = blockIdx.x;
  int t = threadIdx.x;
  const float* yr = yg + (size_t)row * DI;
  float v0 = yr[t], v1 = yr[t + 128], v2 = yr[t + 256];
  float s1 = v0 + v1 + v2, s2 = v0 * v0 + v1 * v1 + v2 * v2;
#pragma unroll
  for (int off = 32; off; off >>= 1) {
    s1 += __shfl_xor(s1, off, 64);
    s2 += __shfl_xor(s2, off, 64);
  }
  __shared__ float a1[2], a2[2];
  if ((t & 63) == 0) { a1[t >> 6] = s1; a2[t >> 6] = s2; }
  __syncthreads();
  float t1 = a1[0] + a1[1], t2 = a2[0] + a2[1];
  float mu = t1 / 384.f, var = t2 / 384.f - mu * mu;
  float rstd = rsqrtf(var + 1e-5f);
  float* yo = yn + (size_t)row * DI;
  yo[t]       = (v0 - mu) * rstd * nw[t]       + nb[t];
  yo[t + 128] = (v1 - mu) * rstd * nw[t + 128] + nb[t + 128];
  yo[t + 256] = (v2 - mu) * rstd * nw[t + 256] + nb[t + 256];
}

// ---------------------------------------------------------------------------
// K8: fused 7x7 depthwise conv + bilinear 4x upsample of ssm + gated combine.
// ---------------------------------------------------------------------------
__global__ __launch_bounds__(256) void k_final(
    const float* __restrict__ x, const float* __restrict__ dww, const float* __restrict__ dwb,
    const float* __restrict__ ssm, const float* __restrict__ gate,
    float* __restrict__ out)
{
  int blk = blockIdx.x;
  int ti = blk & 3;
  int c = (blk >> 2) % C_;
  int b = blk / (4 * C_);
  int h0 = ti * 16;
  __shared__ float xpatch[22 * 72];
  __shared__ float wlds[49];
  __shared__ float slds[6 * 16];
  __shared__ float biass;
  int tid = threadIdx.x;
  if (tid < 49) wlds[tid] = dww[(size_t)c * 49 + tid];
  if (tid == 49) biass = dwb[c];
  int ibase = (h0 >> 2) - 1;   // floor(h0*0.25 - 0.375)
  if (tid < 96) {
    int ii = ibase + (tid >> 4);
    ii = ii < 0 ? 0 : (ii > 15 ? 15 : ii);
    int jj = tid & 15;
    slds[tid] = ssm[((size_t)(b * LS) + ii * 16 + jj) * C_ + c];
  }
  const float* xb = x + ((size_t)(b * C_ + c) * Hh) * Ww;
  for (int idx = tid; idx < 22 * 70; idx += 256) {
    int r = idx / 70, col = idx % 70;
    int gh = h0 - 3 + r, gw = col - 3;
    float v = 0.f;
    if (gh >= 0 && gh < 64 && gw >= 0 && gw < 64)
      v = xb[gh * 64 + gw];
    xpatch[r * 72 + col] = v;
  }
  __syncthreads();
  float g = 1.f / (1.f + expf(-gate[0]));
  int qn = tid >> 5;             // 0..7
  int R0 = qn * 2;
  int w0 = (tid & 31) * 2;
  float a00 = 0, a01 = 0, a10 = 0, a11 = 0;
#pragma unroll
  for (int k = 0; k < 8; ++k) {
    const float* prow = &xpatch[(R0 + k) * 72 + w0];
    float v[8];
#pragma unroll
    for (int d = 0; d < 8; ++d) v[d] = prow[d];
    if (k < 7) {
#pragma unroll
      for (int dx = 0; dx < 7; ++dx) {
        float wv = wlds[k * 7 + dx];
        a00 += wv * v[dx]; a01 += wv * v[dx + 1];
      }
    }
    if (k > 0) {
#pragma unroll
      for (int dx = 0; dx < 7; ++dx) {
        float wv = wlds[(k - 1) * 7 + dx];
        a10 += wv * v[dx]; a11 += wv * v[dx + 1];
      }
    }
  }
  float locs[2][2] = {{a00 + biass, a01 + biass}, {a10 + biass, a11 + biass}};
  float* orow = out + ((size_t)(b * C_ + c) * Hh) * Ww;
#pragma unroll
  for (int rr = 0; rr < 2; ++rr) {
    int hgl = h0 + R0 + rr;
    float ci = hgl * 0.25f - 0.375f;
    float fif = floorf(ci);
    int i0 = (int)fif;
    float fi = ci - fif;
    int li = i0 - ibase;
    const float* r0p = &slds[li * 16];
    const float* r1p = &slds[(li + 1) * 16];
    float ov[2];
#pragma unroll
    for (int ccx = 0; ccx < 2; ++ccx) {
      int wgl = w0 + ccx;
      float cj = wgl * 0.25f - 0.375f;
      float fjf = floorf(cj);
      int j0 = (int)fjf;
      float fj = cj - fjf;
      int jc0 = j0 < 0 ? 0 : j0;
      int jc1 = (j0 + 1) > 15 ? 15 : (j0 + 1);
      float sv = (1.f - fi) * ((1.f - fj) * r0p[jc0] + fj * r0p[jc1])
               +         fi * ((1.f - fj) * r1p[jc0] + fj * r1p[jc1]);
      float xv = xpatch[(R0 + rr + 3) * 72 + (wgl + 3)];
      ov[ccx] = xv + g * sv + (1.f - g) * locs[rr][ccx];
    }
    *reinterpret_cast<float2*>(&orow[hgl * 64 + w0]) = make_float2(ov[0], ov[1]);
  }
}

// ---------------------------------------------------------------------------
extern "C" void kernel_launch(void* const* d_in, const int* in_sizes, int n_in,
                              void* d_out, int out_size, void* d_ws, size_t ws_size,
                              hipStream_t stream)
{
  const float* x    = (const float*)d_in[0];
  const float* inw  = (const float*)d_in[1];
  const float* xw   = (const float*)d_in[2];
  const float* dtw  = (const float*)d_in[3];
  const float* dtb  = (const float*)d_in[4];
  const float* cw   = (const float*)d_in[5];
  const float* cb   = (const float*)d_in[6];
  const float* alog = (const float*)d_in[7];
  const float* Dp   = (const float*)d_in[8];
  const float* ow   = (const float*)d_in[9];
  const float* nsw  = (const float*)d_in[10];
  const float* nsb  = (const float*)d_in[11];
  const float* n1w  = (const float*)d_in[12];
  const float* n1b  = (const float*)d_in[13];
  const float* dww  = (const float*)d_in[14];
  const float* dwb  = (const float*)d_in[15];
  const float* gate = (const float*)d_in[16];

  char* ws = (char*)d_ws;
  float* xln   = (float*)ws; ws += (size_t)8192 * 192 * 4;   // 6.3 MB
  float* xz    = (float*)ws; ws += (size_t)8192 * 768 * 4;   // 25.2 MB
  float* xc    = (float*)ws; ws += (size_t)8192 * 384 * 4;   // 12.6 MB
  float* delta = (float*)ws; ws += (size_t)8192 * 384 * 4;   // 12.6 MB
  float* BC    = (float*)ws; ws += (size_t)8192 * 32 * 4;    // 1.05 MB
  float* yg    = (float*)ws; ws += (size_t)8192 * 384 * 4;   // 12.6 MB
  float* yn  = xz;    // alias: xz dead after k_scan
  float* ssm = xln;   // alias: xln dead after gemm1

  k_pool_ln<<<B_ * 16, 256, 0, stream>>>(x, n1w, n1b, xln);
  k_gemm_f32<<<dim3(6, 64), 256, 0, stream>>>(xln, inw, xz, 768, 192);
  k_conv_silu<<<12288, 256, 0, stream>>>(xz, cw, cb, xc);
  k_xproj<<<2048, 256, 0, stream>>>(xc, xw, dtw, dtb, BC, delta);
  k_scan<<<B_ * 24, 256, 0, stream>>>(delta, xc, BC, xz, alog, Dp, yg);
  k_ln_ssm<<<8192, 128, 0, stream>>>(yg, nsw, nsb, yn);
  k_gemm_f32<<<dim3(2, 64), 256, 0, stream>>>(yn, ow, ssm, 192, 384);
  k_final<<<24576, 256, 0, stream>>>(x, dww, dwb, ssm, gate, (float*)d_out);
}

// Round 3
// 477.749 us; speedup vs baseline: 1.2849x; 1.0946x over previous
//
#include <hip/hip_runtime.h>
#include <stdint.h>

// Problem constants (fixed by setup_inputs shapes)
#define B_   32
#define C_   192
#define Hh   64
#define Ww   64
#define LS   256    // 16*16 pooled positions
#define DI   384    // d_inner
#define DSt  16     // d_state
#define E2   768    // 2*d_inner

// ---------------------------------------------------------------------------
// K1 v2: 4x4 avg-pool + LayerNorm over C=192, coalesced.
// ---------------------------------------------------------------------------
__global__ __launch_bounds__(256) void k_pool_ln(
    const float* __restrict__ x, const float* __restrict__ w, const float* __restrict__ bb,
    float* __restrict__ xln)
{
  int b = blockIdx.x >> 4, i = blockIdx.x & 15;
  int tid = threadIdx.x;
  int wv = tid >> 6;          // wave id 0..3 -> channel sub-index
  int off = tid & 63;         // float4 slot within the 4x64 region
  int j = off & 15;           // pooled col

  __shared__ float pooledT[16 * 193];   // [j][c], pitch 193 -> conflict-free
  __shared__ float red1[4][16], red2[4][16];
  __shared__ float muL[16], rsL[16];

  const float* xbase = x + (((size_t)(b * C_) * Hh + i * 4) * Ww);
#pragma unroll 4
  for (int cc = 0; cc < 48; ++cc) {
    int c = cc * 4 + wv;
    float4 v = *reinterpret_cast<const float4*>(xbase + (size_t)c * (Hh * Ww) + off * 4);
    float s = v.x + v.y + v.z + v.w;
    s += __shfl_xor(s, 16, 64);   // sum over row r (bits 4..5 of off)
    s += __shfl_xor(s, 32, 64);
    if (off < 16) pooledT[j * 193 + c] = s * (1.f / 16.f);
  }
  __syncthreads();

  // LN stats over c for each of the 16 pooled cols j.
  int j2 = tid & 15, cg = tid >> 4;   // cg 0..15, each sums 12 channels
  float s1 = 0.f, s2 = 0.f;
#pragma unroll
  for (int ccx = 0; ccx < 12; ++ccx) {
    float v = pooledT[j2 * 193 + cg * 12 + ccx];
    s1 += v; s2 += v * v;
  }
  s1 += __shfl_xor(s1, 16, 64); s1 += __shfl_xor(s1, 32, 64);
  s2 += __shfl_xor(s2, 16, 64); s2 += __shfl_xor(s2, 32, 64);
  if ((tid & 63) < 16) { red1[tid >> 6][j2] = s1; red2[tid >> 6][j2] = s2; }
  __syncthreads();
  if (tid < 16) {
    float t1 = red1[0][tid] + red1[1][tid] + red1[2][tid] + red1[3][tid];
    float t2 = red2[0][tid] + red2[1][tid] + red2[2][tid] + red2[3][tid];
    float mu = t1 / 192.f;
    float var = t2 / 192.f - mu * mu;
    muL[tid] = mu; rsL[tid] = rsqrtf(var + 1e-5f);
  }
  __syncthreads();

#pragma unroll
  for (int k = 0; k < 12; ++k) {
    int o = tid + 256 * k;          // 0..3071
    int c = o % 192, jj = o / 192;
    float v = (pooledT[jj * 193 + c] - muL[jj]) * rsL[jj] * w[c] + bb[c];
    xln[((size_t)(b * 256 + i * 16 + jj)) * C_ + c] = v;
  }
}

// ---------------------------------------------------------------------------
// K2/K7: f32 NT GEMM. C[m,n] = sum_k A[m,k]*W[n,k].
// 128x128 block tile, BK=8, 256 threads, 8x8 register tile per thread.
// ---------------------------------------------------------------------------
__global__ __launch_bounds__(256) void k_gemm_f32(
    const float* __restrict__ A, const float* __restrict__ W,
    float* __restrict__ C, int N, int K)
{
  __shared__ float At[8][132];
  __shared__ float Wt[8][132];
  int tid = threadIdx.x;
  int m0 = blockIdx.y * 128, n0 = blockIdx.x * 128;
  int tx = tid & 15, ty = tid >> 4;
  int lr = tid >> 1, lk = (tid & 1) * 4;
  float acc[8][8] = {};
  const float* Arow = A + (size_t)(m0 + lr) * K + lk;
  int wrow = n0 + lr; if (wrow >= N) wrow = N - 1;
  const float* Wrow = W + (size_t)wrow * K + lk;
  for (int k0 = 0; k0 < K; k0 += 8) {
    float4 av = *reinterpret_cast<const float4*>(Arow + k0);
    float4 wv = *reinterpret_cast<const float4*>(Wrow + k0);
    __syncthreads();
    At[lk + 0][lr] = av.x; At[lk + 1][lr] = av.y; At[lk + 2][lr] = av.z; At[lk + 3][lr] = av.w;
    Wt[lk + 0][lr] = wv.x; Wt[lk + 1][lr] = wv.y; Wt[lk + 2][lr] = wv.z; Wt[lk + 3][lr] = wv.w;
    __syncthreads();
#pragma unroll
    for (int k = 0; k < 8; ++k) {
      float4 a0 = *reinterpret_cast<const float4*>(&At[k][8 * ty]);
      float4 a1 = *reinterpret_cast<const float4*>(&At[k][8 * ty + 4]);
      float4 w0 = *reinterpret_cast<const float4*>(&Wt[k][8 * tx]);
      float4 w1 = *reinterpret_cast<const float4*>(&Wt[k][8 * tx + 4]);
      float a[8] = {a0.x, a0.y, a0.z, a0.w, a1.x, a1.y, a1.z, a1.w};
      float w[8] = {w0.x, w0.y, w0.z, w0.w, w1.x, w1.y, w1.z, w1.w};
#pragma unroll
      for (int i = 0; i < 8; ++i)
#pragma unroll
        for (int j = 0; j < 8; ++j) acc[i][j] += a[i] * w[j];
    }
  }
#pragma unroll
  for (int i = 0; i < 8; ++i) {
    int row = m0 + 8 * ty + i;
    int col0 = n0 + 8 * tx;
    if (col0 < N)
      *reinterpret_cast<float4*>(C + (size_t)row * N + col0) =
          make_float4(acc[i][0], acc[i][1], acc[i][2], acc[i][3]);
    if (col0 + 4 < N)
      *reinterpret_cast<float4*>(C + (size_t)row * N + col0 + 4) =
          make_float4(acc[i][4], acc[i][5], acc[i][6], acc[i][7]);
  }
}

// ---------------------------------------------------------------------------
// K3: depthwise conv1d (k=3, zero pad) over seq + SiLU. One thread per (b,l,e).
// ---------------------------------------------------------------------------
__global__ __launch_bounds__(256) void k_conv_silu(
    const float* __restrict__ xz, const float* __restrict__ cw, const float* __restrict__ cb,
    float* __restrict__ xc)
{
  int idx = blockIdx.x * 256 + threadIdx.x;   // (b*256+l)*384 + e
  int e = idx % DI;
  int row = idx / DI;
  int l = row & 255;
  const float* xin = xz + (size_t)row * E2 + e;
  float x0 = *xin;
  float xm = (l > 0)   ? *(xin - E2) : 0.f;
  float xp = (l < 255) ? *(xin + E2) : 0.f;
  float v = cw[e * 3 + 0] * xm + cw[e * 3 + 1] * x0 + cw[e * 3 + 2] * xp + cb[e];
  xc[idx] = v / (1.f + expf(-v));
}

// ---------------------------------------------------------------------------
// K4: x_proj (33 dots of len 384) + dt_proj + softplus. One wave per (b,l) row.
// ---------------------------------------------------------------------------
__global__ __launch_bounds__(256) void k_xproj(
    const float* __restrict__ xc, const float* __restrict__ xw,
    const float* __restrict__ dtw, const float* __restrict__ dtb,
    float* __restrict__ BC, float* __restrict__ delta)
{
  int wid = threadIdx.x >> 6, lane = threadIdx.x & 63;
  int row = blockIdx.x * 4 + wid;
  const float* xr = xc + (size_t)row * DI;
  float xv[6];
#pragma unroll
  for (int k = 0; k < 6; ++k) xv[k] = xr[lane + 64 * k];
  float dres = 0.f, mine = 0.f;
  for (int j = 0; j < 33; ++j) {
    const float* wr = xw + (size_t)j * DI;
    float p = 0.f;
#pragma unroll
    for (int k = 0; k < 6; ++k) p += wr[lane + 64 * k] * xv[k];
#pragma unroll
    for (int off = 32; off; off >>= 1) p += __shfl_xor(p, off, 64);
    if (j == 0) dres = p;
    else if (lane == j - 1) mine = p;
  }
  if (lane < 32) BC[(size_t)row * 32 + lane] = mine;   // [0..15]=B_mat, [16..31]=C_mat
#pragma unroll
  for (int k = 0; k < 6; ++k) {
    int e = lane + 64 * k;
    float dr = dres * dtw[e] + dtb[e];
    delta[(size_t)row * DI + e] = dr > 20.f ? dr : log1pf(expf(dr));
  }
}

// ---------------------------------------------------------------------------
// K5 v3: selective scan, 16-step batched with LDS transpose reduction.
// Old v2 was issue-bound: ~116 VALU slots/step (4 chained ds_bpermute
// shuffles, full expf + precise divide for silu(z) discarded by 15/16
// lanes). New: per 16-step group, stage 16x(delta,xc,B,C) in registers
// (64 independent loads), run the h-recurrence in-register (only 16
// chained FMAs serial), write ph[i] = h*C + xc*D/16 to LDS [et][i][s]
// (pitch 20: rows 80B -> float4-aligned), then lane (et,s) reads its
// contiguous row [et][s][0..15] with 4x ds_read_b128, sums -> y(l0+s),
// applies silu(z) and stores — silu/divide/store once per 16 steps,
// all 64 lanes productive, zero shuffles.
// ---------------------------------------------------------------------------
__global__ __launch_bounds__(256) void k_scan(
    const float* __restrict__ delta, const float* __restrict__ xc,
    const float* __restrict__ BC, const float* __restrict__ xz,
    const float* __restrict__ A_log, const float* __restrict__ Dp,
    float* __restrict__ yg)
{
  int blk = blockIdx.x;            // b*24 + eg
  int b = blk / 24, eg = blk - b * 24;
  int tid = threadIdx.x;
  int et = tid >> 4, s = tid & 15;
  int e = eg * 16 + et;
  float Aes = -expf(A_log[e * DSt + s]);
  float Dv16 = Dp[e] * (1.f / 16.f);

  // Block-uniform bases (SGPR) + 32-bit lane offsets.
  const float* dbase  = delta + (size_t)b * 256 * DI;
  const float* xbase  = xc    + (size_t)b * 256 * DI;
  const float* bcbase = BC    + (size_t)b * 256 * 32;
  const float* zbase  = xz    + (size_t)b * 256 * E2 + DI;
  float*       ybase  = yg    + (size_t)b * 256 * DI;

  __shared__ float tr[16 * 16 * 20];             // [et][i][s], pitch 20 words
  float* myw = &tr[(et * 16) * 20 + s];          // write slot: + i*20
  const float* myr = &tr[(et * 16 + s) * 20];    // read row: 80B-aligned

  float h = 0.f;
  for (int g = 0; g < 16; ++g) {
    int l0 = g * 16;
    float dv[16], xv[16], Bm[16], Cm[16];
#pragma unroll
    for (int i = 0; i < 16; ++i) {
      int row = l0 + i;
      dv[i] = dbase[row * DI + e];
      xv[i] = xbase[row * DI + e];
      Bm[i] = bcbase[row * 32 + s];
      Cm[i] = bcbase[row * 32 + 16 + s];
    }
    __syncthreads();   // WAR: previous group's LDS reads done before overwrite
#pragma unroll
    for (int i = 0; i < 16; ++i) {
      float da = __expf(dv[i] * Aes);
      h = da * h + dv[i] * Bm[i] * xv[i];
      myw[i * 20] = h * Cm[i] + xv[i] * Dv16;
    }
    __syncthreads();
    // lane (et,s) finishes step l = l0 + s
    float4 p0 = *reinterpret_cast<const float4*>(myr + 0);
    float4 p1 = *reinterpret_cast<const float4*>(myr + 4);
    float4 p2 = *reinterpret_cast<const float4*>(myr + 8);
    float4 p3 = *reinterpret_cast<const float4*>(myr + 12);
    float S = ((p0.x + p0.y) + (p0.z + p0.w)) + ((p1.x + p1.y) + (p1.z + p1.w))
            + ((p2.x + p2.y) + (p2.z + p2.w)) + ((p3.x + p3.y) + (p3.z + p3.w));
    int l = l0 + s;
    float zv = zbase[l * E2 + e];
    float y = S * (zv / (1.f + __expf(-zv)));
    ybase[l * DI + e] = y;
  }
}

// ---------------------------------------------------------------------------
// K6: LayerNorm over d_inner=384, f32 out.
// ---------------------------------------------------------------------------
__global__ __launch_bounds__(128) void k_ln_ssm(
    const float* __restrict__ yg, const float* __restrict__ nw, const float* __restrict__ nb,
    float* __restrict__ yn)
{
  int row = blockIdx.x;
  int t = threadIdx.x;
  const float* yr = yg + (size_t)row * DI;
  float v0 = yr[t], v1 = yr[t + 128], v2 = yr[t + 256];
  float s1 = v0 + v1 + v2, s2 = v0 * v0 + v1 * v1 + v2 * v2;
#pragma unroll
  for (int off = 32; off; off >>= 1) {
    s1 += __shfl_xor(s1, off, 64);
    s2 += __shfl_xor(s2, off, 64);
  }
  __shared__ float a1[2], a2[2];
  if ((t & 63) == 0) { a1[t >> 6] = s1; a2[t >> 6] = s2; }
  __syncthreads();
  float t1 = a1[0] + a1[1], t2 = a2[0] + a2[1];
  float mu = t1 / 384.f, var = t2 / 384.f - mu * mu;
  float rstd = rsqrtf(var + 1e-5f);
  float* yo = yn + (size_t)row * DI;
  yo[t]       = (v0 - mu) * rstd * nw[t]       + nb[t];
  yo[t + 128] = (v1 - mu) * rstd * nw[t + 128] + nb[t + 128];
  yo[t + 256] = (v2 - mu) * rstd * nw[t + 256] + nb[t + 256];
}

// ---------------------------------------------------------------------------
// K8: fused 7x7 depthwise conv + bilinear 4x upsample of ssm + gated combine.
// ---------------------------------------------------------------------------
__global__ __launch_bounds__(256) void k_final(
    const float* __restrict__ x, const float* __restrict__ dww, const float* __restrict__ dwb,
    const float* __restrict__ ssm, const float* __restrict__ gate,
    float* __restrict__ out)
{
  int blk = blockIdx.x;
  int ti = blk & 3;
  int c = (blk >> 2) % C_;
  int b = blk / (4 * C_);
  int h0 = ti * 16;
  __shared__ float xpatch[22 * 72];
  __shared__ float wlds[49];
  __shared__ float slds[6 * 16];
  __shared__ float biass;
  int tid = threadIdx.x;
  if (tid < 49) wlds[tid] = dww[(size_t)c * 49 + tid];
  if (tid == 49) biass = dwb[c];
  int ibase = (h0 >> 2) - 1;   // floor(h0*0.25 - 0.375)
  if (tid < 96) {
    int ii = ibase + (tid >> 4);
    ii = ii < 0 ? 0 : (ii > 15 ? 15 : ii);
    int jj = tid & 15;
    slds[tid] = ssm[((size_t)(b * LS) + ii * 16 + jj) * C_ + c];
  }
  const float* xb = x + ((size_t)(b * C_ + c) * Hh) * Ww;
  for (int idx = tid; idx < 22 * 70; idx += 256) {
    int r = idx / 70, col = idx % 70;
    int gh = h0 - 3 + r, gw = col - 3;
    float v = 0.f;
    if (gh >= 0 && gh < 64 && gw >= 0 && gw < 64)
      v = xb[gh * 64 + gw];
    xpatch[r * 72 + col] = v;
  }
  __syncthreads();
  float g = 1.f / (1.f + expf(-gate[0]));
  int qn = tid >> 5;             // 0..7
  int R0 = qn * 2;
  int w0 = (tid & 31) * 2;
  float a00 = 0, a01 = 0, a10 = 0, a11 = 0;
#pragma unroll
  for (int k = 0; k < 8; ++k) {
    const float* prow = &xpatch[(R0 + k) * 72 + w0];
    float v[8];
#pragma unroll
    for (int d = 0; d < 8; ++d) v[d] = prow[d];
    if (k < 7) {
#pragma unroll
      for (int dx = 0; dx < 7; ++dx) {
        float wv = wlds[k * 7 + dx];
        a00 += wv * v[dx]; a01 += wv * v[dx + 1];
      }
    }
    if (k > 0) {
#pragma unroll
      for (int dx = 0; dx < 7; ++dx) {
        float wv = wlds[(k - 1) * 7 + dx];
        a10 += wv * v[dx]; a11 += wv * v[dx + 1];
      }
    }
  }
  float locs[2][2] = {{a00 + biass, a01 + biass}, {a10 + biass, a11 + biass}};
  float* orow = out + ((size_t)(b * C_ + c) * Hh) * Ww;
#pragma unroll
  for (int rr = 0; rr < 2; ++rr) {
    int hgl = h0 + R0 + rr;
    float ci = hgl * 0.25f - 0.375f;
    float fif = floorf(ci);
    int i0 = (int)fif;
    float fi = ci - fif;
    int li = i0 - ibase;
    const float* r0p = &slds[li * 16];
    const float* r1p = &slds[(li + 1) * 16];
    float ov[2];
#pragma unroll
    for (int ccx = 0; ccx < 2; ++ccx) {
      int wgl = w0 + ccx;
      float cj = wgl * 0.25f - 0.375f;
      float fjf = floorf(cj);
      int j0 = (int)fjf;
      float fj = cj - fjf;
      int jc0 = j0 < 0 ? 0 : j0;
      int jc1 = (j0 + 1) > 15 ? 15 : (j0 + 1);
      float sv = (1.f - fi) * ((1.f - fj) * r0p[jc0] + fj * r0p[jc1])
               +         fi * ((1.f - fj) * r1p[jc0] + fj * r1p[jc1]);
      float xv = xpatch[(R0 + rr + 3) * 72 + (wgl + 3)];
      ov[ccx] = xv + g * sv + (1.f - g) * locs[rr][ccx];
    }
    *reinterpret_cast<float2*>(&orow[hgl * 64 + w0]) = make_float2(ov[0], ov[1]);
  }
}

// ---------------------------------------------------------------------------
extern "C" void kernel_launch(void* const* d_in, const int* in_sizes, int n_in,
                              void* d_out, int out_size, void* d_ws, size_t ws_size,
                              hipStream_t stream)
{
  const float* x    = (const float*)d_in[0];
  const float* inw  = (const float*)d_in[1];
  const float* xw   = (const float*)d_in[2];
  const float* dtw  = (const float*)d_in[3];
  const float* dtb  = (const float*)d_in[4];
  const float* cw   = (const float*)d_in[5];
  const float* cb   = (const float*)d_in[6];
  const float* alog = (const float*)d_in[7];
  const float* Dp   = (const float*)d_in[8];
  const float* ow   = (const float*)d_in[9];
  const float* nsw  = (const float*)d_in[10];
  const float* nsb  = (const float*)d_in[11];
  const float* n1w  = (const float*)d_in[12];
  const float* n1b  = (const float*)d_in[13];
  const float* dww  = (const float*)d_in[14];
  const float* dwb  = (const float*)d_in[15];
  const float* gate = (const float*)d_in[16];

  char* ws = (char*)d_ws;
  float* xln   = (float*)ws; ws += (size_t)8192 * 192 * 4;   // 6.3 MB
  float* xz    = (float*)ws; ws += (size_t)8192 * 768 * 4;   // 25.2 MB
  float* xc    = (float*)ws; ws += (size_t)8192 * 384 * 4;   // 12.6 MB
  float* delta = (float*)ws; ws += (size_t)8192 * 384 * 4;   // 12.6 MB
  float* BC    = (float*)ws; ws += (size_t)8192 * 32 * 4;    // 1.05 MB
  float* yg    = (float*)ws; ws += (size_t)8192 * 384 * 4;   // 12.6 MB
  float* yn  = xz;    // alias: xz dead after k_scan
  float* ssm = xln;   // alias: xln dead after gemm1

  k_pool_ln<<<B_ * 16, 256, 0, stream>>>(x, n1w, n1b, xln);
  k_gemm_f32<<<dim3(6, 64), 256, 0, stream>>>(xln, inw, xz, 768, 192);
  k_conv_silu<<<12288, 256, 0, stream>>>(xz, cw, cb, xc);
  k_xproj<<<2048, 256, 0, stream>>>(xc, xw, dtw, dtb, BC, delta);
  k_scan<<<B_ * 24, 256, 0, stream>>>(delta, xc, BC, xz, alog, Dp, yg);
  k_ln_ssm<<<8192, 128, 0, stream>>>(yg, nsw, nsb, yn);
  k_gemm_f32<<<dim3(2, 64), 256, 0, stream>>>(yn, ow, ssm, 192, 384);
  k_final<<<24576, 256, 0, stream>>>(x, dww, dwb, ssm, gate, (float*)d_out);
}

// Round 4
// 449.540 us; speedup vs baseline: 1.3656x; 1.0628x over previous
//
#include <hip/hip_runtime.h>
#include <stdint.h>

// Problem constants (fixed by setup_inputs shapes)
#define B_   32
#define C_   192
#define Hh   64
#define Ww   64
#define LS   256    // 16*16 pooled positions
#define DI   384    // d_inner
#define DSt  16     // d_state
#define E2   768    // 2*d_inner

// ---------------------------------------------------------------------------
// K1 v2: 4x4 avg-pool + LayerNorm over C=192, coalesced.
// ---------------------------------------------------------------------------
__global__ __launch_bounds__(256) void k_pool_ln(
    const float* __restrict__ x, const float* __restrict__ w, const float* __restrict__ bb,
    float* __restrict__ xln)
{
  int b = blockIdx.x >> 4, i = blockIdx.x & 15;
  int tid = threadIdx.x;
  int wv = tid >> 6;          // wave id 0..3 -> channel sub-index
  int off = tid & 63;         // float4 slot within the 4x64 region
  int j = off & 15;           // pooled col

  __shared__ float pooledT[16 * 193];   // [j][c], pitch 193 -> conflict-free
  __shared__ float red1[4][16], red2[4][16];
  __shared__ float muL[16], rsL[16];

  const float* xbase = x + (((size_t)(b * C_) * Hh + i * 4) * Ww);
#pragma unroll 4
  for (int cc = 0; cc < 48; ++cc) {
    int c = cc * 4 + wv;
    float4 v = *reinterpret_cast<const float4*>(xbase + (size_t)c * (Hh * Ww) + off * 4);
    float s = v.x + v.y + v.z + v.w;
    s += __shfl_xor(s, 16, 64);   // sum over row r (bits 4..5 of off)
    s += __shfl_xor(s, 32, 64);
    if (off < 16) pooledT[j * 193 + c] = s * (1.f / 16.f);
  }
  __syncthreads();

  // LN stats over c for each of the 16 pooled cols j.
  int j2 = tid & 15, cg = tid >> 4;   // cg 0..15, each sums 12 channels
  float s1 = 0.f, s2 = 0.f;
#pragma unroll
  for (int ccx = 0; ccx < 12; ++ccx) {
    float v = pooledT[j2 * 193 + cg * 12 + ccx];
    s1 += v; s2 += v * v;
  }
  s1 += __shfl_xor(s1, 16, 64); s1 += __shfl_xor(s1, 32, 64);
  s2 += __shfl_xor(s2, 16, 64); s2 += __shfl_xor(s2, 32, 64);
  if ((tid & 63) < 16) { red1[tid >> 6][j2] = s1; red2[tid >> 6][j2] = s2; }
  __syncthreads();
  if (tid < 16) {
    float t1 = red1[0][tid] + red1[1][tid] + red1[2][tid] + red1[3][tid];
    float t2 = red2[0][tid] + red2[1][tid] + red2[2][tid] + red2[3][tid];
    float mu = t1 / 192.f;
    float var = t2 / 192.f - mu * mu;
    muL[tid] = mu; rsL[tid] = rsqrtf(var + 1e-5f);
  }
  __syncthreads();

#pragma unroll
  for (int k = 0; k < 12; ++k) {
    int o = tid + 256 * k;          // 0..3071
    int c = o % 192, jj = o / 192;
    float v = (pooledT[jj * 193 + c] - muL[jj]) * rsL[jj] * w[c] + bb[c];
    xln[((size_t)(b * 256 + i * 16 + jj)) * C_ + c] = v;
  }
}

// ---------------------------------------------------------------------------
// K2/K7: f32 NT GEMM. C[m,n] = sum_k A[m,k]*W[n,k].
// 128x128 block tile, BK=8, 256 threads, 8x8 register tile per thread.
// ---------------------------------------------------------------------------
__global__ __launch_bounds__(256) void k_gemm_f32(
    const float* __restrict__ A, const float* __restrict__ W,
    float* __restrict__ C, int N, int K)
{
  __shared__ float At[8][132];
  __shared__ float Wt[8][132];
  int tid = threadIdx.x;
  int m0 = blockIdx.y * 128, n0 = blockIdx.x * 128;
  int tx = tid & 15, ty = tid >> 4;
  int lr = tid >> 1, lk = (tid & 1) * 4;
  float acc[8][8] = {};
  const float* Arow = A + (size_t)(m0 + lr) * K + lk;
  int wrow = n0 + lr; if (wrow >= N) wrow = N - 1;
  const float* Wrow = W + (size_t)wrow * K + lk;
  for (int k0 = 0; k0 < K; k0 += 8) {
    float4 av = *reinterpret_cast<const float4*>(Arow + k0);
    float4 wv = *reinterpret_cast<const float4*>(Wrow + k0);
    __syncthreads();
    At[lk + 0][lr] = av.x; At[lk + 1][lr] = av.y; At[lk + 2][lr] = av.z; At[lk + 3][lr] = av.w;
    Wt[lk + 0][lr] = wv.x; Wt[lk + 1][lr] = wv.y; Wt[lk + 2][lr] = wv.z; Wt[lk + 3][lr] = wv.w;
    __syncthreads();
#pragma unroll
    for (int k = 0; k < 8; ++k) {
      float4 a0 = *reinterpret_cast<const float4*>(&At[k][8 * ty]);
      float4 a1 = *reinterpret_cast<const float4*>(&At[k][8 * ty + 4]);
      float4 w0 = *reinterpret_cast<const float4*>(&Wt[k][8 * tx]);
      float4 w1 = *reinterpret_cast<const float4*>(&Wt[k][8 * tx + 4]);
      float a[8] = {a0.x, a0.y, a0.z, a0.w, a1.x, a1.y, a1.z, a1.w};
      float w[8] = {w0.x, w0.y, w0.z, w0.w, w1.x, w1.y, w1.z, w1.w};
#pragma unroll
      for (int i = 0; i < 8; ++i)
#pragma unroll
        for (int j = 0; j < 8; ++j) acc[i][j] += a[i] * w[j];
    }
  }
#pragma unroll
  for (int i = 0; i < 8; ++i) {
    int row = m0 + 8 * ty + i;
    int col0 = n0 + 8 * tx;
    if (col0 < N)
      *reinterpret_cast<float4*>(C + (size_t)row * N + col0) =
          make_float4(acc[i][0], acc[i][1], acc[i][2], acc[i][3]);
    if (col0 + 4 < N)
      *reinterpret_cast<float4*>(C + (size_t)row * N + col0 + 4) =
          make_float4(acc[i][4], acc[i][5], acc[i][6], acc[i][7]);
  }
}

// ---------------------------------------------------------------------------
// K3: depthwise conv1d (k=3, zero pad) over seq + SiLU. One thread per (b,l,e).
// ---------------------------------------------------------------------------
__global__ __launch_bounds__(256) void k_conv_silu(
    const float* __restrict__ xz, const float* __restrict__ cw, const float* __restrict__ cb,
    float* __restrict__ xc)
{
  int idx = blockIdx.x * 256 + threadIdx.x;   // (b*256+l)*384 + e
  int e = idx % DI;
  int row = idx / DI;
  int l = row & 255;
  const float* xin = xz + (size_t)row * E2 + e;
  float x0 = *xin;
  float xm = (l > 0)   ? *(xin - E2) : 0.f;
  float xp = (l < 255) ? *(xin + E2) : 0.f;
  float v = cw[e * 3 + 0] * xm + cw[e * 3 + 1] * x0 + cw[e * 3 + 2] * xp + cb[e];
  xc[idx] = v / (1.f + expf(-v));
}

// ---------------------------------------------------------------------------
// K4: x_proj (33 dots of len 384) + dt_proj + softplus. One wave per (b,l) row.
// ---------------------------------------------------------------------------
__global__ __launch_bounds__(256) void k_xproj(
    const float* __restrict__ xc, const float* __restrict__ xw,
    const float* __restrict__ dtw, const float* __restrict__ dtb,
    float* __restrict__ BC, float* __restrict__ delta)
{
  int wid = threadIdx.x >> 6, lane = threadIdx.x & 63;
  int row = blockIdx.x * 4 + wid;
  const float* xr = xc + (size_t)row * DI;
  float xv[6];
#pragma unroll
  for (int k = 0; k < 6; ++k) xv[k] = xr[lane + 64 * k];
  float dres = 0.f, mine = 0.f;
  for (int j = 0; j < 33; ++j) {
    const float* wr = xw + (size_t)j * DI;
    float p = 0.f;
#pragma unroll
    for (int k = 0; k < 6; ++k) p += wr[lane + 64 * k] * xv[k];
#pragma unroll
    for (int off = 32; off; off >>= 1) p += __shfl_xor(p, off, 64);
    if (j == 0) dres = p;
    else if (lane == j - 1) mine = p;
  }
  if (lane < 32) BC[(size_t)row * 32 + lane] = mine;   // [0..15]=B_mat, [16..31]=C_mat
#pragma unroll
  for (int k = 0; k < 6; ++k) {
    int e = lane + 64 * k;
    float dr = dres * dtw[e] + dtb[e];
    delta[(size_t)row * DI + e] = dr > 20.f ? dr : log1pf(expf(dr));
  }
}

// ---------------------------------------------------------------------------
// K5 v3: selective scan, 16-step batched with LDS transpose reduction.
// ---------------------------------------------------------------------------
__global__ __launch_bounds__(256) void k_scan(
    const float* __restrict__ delta, const float* __restrict__ xc,
    const float* __restrict__ BC, const float* __restrict__ xz,
    const float* __restrict__ A_log, const float* __restrict__ Dp,
    float* __restrict__ yg)
{
  int blk = blockIdx.x;            // b*24 + eg
  int b = blk / 24, eg = blk - b * 24;
  int tid = threadIdx.x;
  int et = tid >> 4, s = tid & 15;
  int e = eg * 16 + et;
  float Aes = -expf(A_log[e * DSt + s]);
  float Dv16 = Dp[e] * (1.f / 16.f);

  const float* dbase  = delta + (size_t)b * 256 * DI;
  const float* xbase  = xc    + (size_t)b * 256 * DI;
  const float* bcbase = BC    + (size_t)b * 256 * 32;
  const float* zbase  = xz    + (size_t)b * 256 * E2 + DI;
  float*       ybase  = yg    + (size_t)b * 256 * DI;

  __shared__ float tr[16 * 16 * 20];             // [et][i][s], pitch 20 words
  float* myw = &tr[(et * 16) * 20 + s];          // write slot: + i*20
  const float* myr = &tr[(et * 16 + s) * 20];    // read row: 80B-aligned

  float h = 0.f;
  for (int g = 0; g < 16; ++g) {
    int l0 = g * 16;
    float dv[16], xv[16], Bm[16], Cm[16];
#pragma unroll
    for (int i = 0; i < 16; ++i) {
      int row = l0 + i;
      dv[i] = dbase[row * DI + e];
      xv[i] = xbase[row * DI + e];
      Bm[i] = bcbase[row * 32 + s];
      Cm[i] = bcbase[row * 32 + 16 + s];
    }
    __syncthreads();   // WAR: previous group's LDS reads done before overwrite
#pragma unroll
    for (int i = 0; i < 16; ++i) {
      float da = __expf(dv[i] * Aes);
      h = da * h + dv[i] * Bm[i] * xv[i];
      myw[i * 20] = h * Cm[i] + xv[i] * Dv16;
    }
    __syncthreads();
    // lane (et,s) finishes step l = l0 + s
    float4 p0 = *reinterpret_cast<const float4*>(myr + 0);
    float4 p1 = *reinterpret_cast<const float4*>(myr + 4);
    float4 p2 = *reinterpret_cast<const float4*>(myr + 8);
    float4 p3 = *reinterpret_cast<const float4*>(myr + 12);
    float S = ((p0.x + p0.y) + (p0.z + p0.w)) + ((p1.x + p1.y) + (p1.z + p1.w))
            + ((p2.x + p2.y) + (p2.z + p2.w)) + ((p3.x + p3.y) + (p3.z + p3.w));
    int l = l0 + s;
    float zv = zbase[l * E2 + e];
    float y = S * (zv / (1.f + __expf(-zv)));
    ybase[l * DI + e] = y;
  }
}

// ---------------------------------------------------------------------------
// K6: LayerNorm over d_inner=384, f32 out.
// ---------------------------------------------------------------------------
__global__ __launch_bounds__(128) void k_ln_ssm(
    const float* __restrict__ yg, const float* __restrict__ nw, const float* __restrict__ nb,
    float* __restrict__ yn)
{
  int row = blockIdx.x;
  int t = threadIdx.x;
  const float* yr = yg + (size_t)row * DI;
  float v0 = yr[t], v1 = yr[t + 128], v2 = yr[t + 256];
  float s1 = v0 + v1 + v2, s2 = v0 * v0 + v1 * v1 + v2 * v2;
#pragma unroll
  for (int off = 32; off; off >>= 1) {
    s1 += __shfl_xor(s1, off, 64);
    s2 += __shfl_xor(s2, off, 64);
  }
  __shared__ float a1[2], a2[2];
  if ((t & 63) == 0) { a1[t >> 6] = s1; a2[t >> 6] = s2; }
  __syncthreads();
  float t1 = a1[0] + a1[1], t2 = a2[0] + a2[1];
  float mu = t1 / 384.f, var = t2 / 384.f - mu * mu;
  float rstd = rsqrtf(var + 1e-5f);
  float* yo = yn + (size_t)row * DI;
  yo[t]       = (v0 - mu) * rstd * nw[t]       + nb[t];
  yo[t + 128] = (v1 - mu) * rstd * nw[t + 128] + nb[t + 128];
  yo[t + 256] = (v2 - mu) * rstd * nw[t + 256] + nb[t + 256];
}

// ---------------------------------------------------------------------------
// K8 v2: fused 7x7 depthwise conv + bilinear 4x upsample + gated combine,
// full-plane blocks. Old strip version was VALU-bound (75% busy, 9.5M LDS
// bank conflicts, per-pixel bilinear floorf/clamp, idx/70 divisions, 37%
// halo re-staging). New: block = one (b,c) 64x64 plane; conv halo == the
// zero padding -> zero-fill border + aligned float4 interior copy, no
// bounds checks. Thread = 4x4 output tile: per input row 3 aligned
// ds_read_b128 (pitch 72 words: 288*ty % 32 == 0 -> min-aliasing only);
// 49 weights hoisted to regs via block-uniform loads (scalarizable).
// Bilinear: 4x upsample -> i0/fi are compile-time per (i mod 4):
// i0 in {ty-1,ty}, fi in {.625,.875,.125,.375}; 9 LDS reads + constant
// weights. All stores aligned float4.
// ---------------------------------------------------------------------------
__global__ __launch_bounds__(256) void k_final(
    const float* __restrict__ x, const float* __restrict__ dww, const float* __restrict__ dwb,
    const float* __restrict__ ssm, const float* __restrict__ gate,
    float* __restrict__ out)
{
  int blk = blockIdx.x;            // b*C_ + c
  int c = blk % C_;
  int b = blk / C_;
  int tid = threadIdx.x;
  int ty = tid >> 4, tx = tid & 15;

  __shared__ float xpad[70 * 72];  // [r=gh+3][cc=gw+4], cols 0..3,68..71 zero
  __shared__ float sld[256];       // 16x16 ssm tile for this (b,c)

  // Zero-fill whole pad (1260 float4s), stage ssm tile.
  for (int i4 = tid; i4 < 1260; i4 += 256)
    *reinterpret_cast<float4*>(&xpad[i4 * 4]) = make_float4(0.f, 0.f, 0.f, 0.f);
  sld[tid] = ssm[((size_t)(b * LS) + tid) * C_ + c];
  __syncthreads();

  // Interior copy: 64x64 plane -> xpad rows 3..66, cols 4..67 (aligned).
  const float* xb = x + ((size_t)(b * C_ + c) * Hh) * Ww;
#pragma unroll
  for (int k = 0; k < 4; ++k) {
    int idx = tid + 256 * k;       // 0..1023
    int row = idx >> 4, colq = idx & 15;
    float4 v = *reinterpret_cast<const float4*>(xb + row * 64 + colq * 4);
    *reinterpret_cast<float4*>(&xpad[(row + 3) * 72 + 4 + colq * 4]) = v;
  }

  // Weights (block-uniform -> scalar regs) + bias + gate.
  float wr[49];
#pragma unroll
  for (int k = 0; k < 49; ++k) wr[k] = dww[(size_t)c * 49 + k];
  float bias = dwb[c];
  float g = 1.f / (1.f + __expf(-gate[0]));
  __syncthreads();

  // 7x7 conv for the 4x4 tile at rows 4ty.., cols 4tx..
  float acc[4][4] = {};
  const float* rowbase = &xpad[(4 * ty) * 72 + 4 * tx];
#pragma unroll
  for (int rr = 0; rr < 10; ++rr) {
    float4 v0 = *reinterpret_cast<const float4*>(rowbase + rr * 72);
    float4 v1 = *reinterpret_cast<const float4*>(rowbase + rr * 72 + 4);
    float4 v2 = *reinterpret_cast<const float4*>(rowbase + rr * 72 + 8);
    float v[12] = {v0.x, v0.y, v0.z, v0.w, v1.x, v1.y, v1.z, v1.w, v2.x, v2.y, v2.z, v2.w};
#pragma unroll
    for (int i = 0; i < 4; ++i) {
      if (rr - i < 0 || rr - i > 6) continue;   // compile-time (rr,i unrolled)
      int dy = rr - i;
#pragma unroll
      for (int dx = 0; dx < 7; ++dx) {
        float wv = wr[dy * 7 + dx];
#pragma unroll
        for (int j = 0; j < 4; ++j)
          acc[i][j] += wv * v[j + dx + 1];
      }
    }
  }

  // Bilinear 4x upsample: static weights. Source rows ty-1,ty,ty+1 (clamped),
  // cols tx-1,tx,tx+1 (clamped).
  int rA = ty - 1 < 0 ? 0 : ty - 1;
  int rC = ty + 1 > 15 ? 15 : ty + 1;
  int cA = tx - 1 < 0 ? 0 : tx - 1;
  int cC = tx + 1 > 15 ? 15 : tx + 1;
  float sA0 = sld[rA * 16 + cA], sA1 = sld[rA * 16 + tx], sA2 = sld[rA * 16 + cC];
  float sB0 = sld[ty * 16 + cA], sB1 = sld[ty * 16 + tx], sB2 = sld[ty * 16 + cC];
  float sC0 = sld[rC * 16 + cA], sC1 = sld[rC * 16 + tx], sC2 = sld[rC * 16 + cC];
  // Horizontal interp per source row: j=0:.375L+.625M, 1:.125L+.875M,
  // 2:.875M+.125R, 3:.625M+.375R
  float hA[4] = {0.375f * sA0 + 0.625f * sA1, 0.125f * sA0 + 0.875f * sA1,
                 0.875f * sA1 + 0.125f * sA2, 0.625f * sA1 + 0.375f * sA2};
  float hB[4] = {0.375f * sB0 + 0.625f * sB1, 0.125f * sB0 + 0.875f * sB1,
                 0.875f * sB1 + 0.125f * sB2, 0.625f * sB1 + 0.375f * sB2};
  float hC[4] = {0.375f * sC0 + 0.625f * sC1, 0.125f * sC0 + 0.875f * sC1,
                 0.875f * sC1 + 0.125f * sC2, 0.625f * sC1 + 0.375f * sC2};
  // Vertical weights per output row i: {.375A+.625B, .125A+.875B,
  // .875B+.125C, .625B+.375C}
  float viA[4] = {0.375f, 0.125f, 0.f, 0.f};
  float viB[4] = {0.625f, 0.875f, 0.875f, 0.625f};
  float viC[4] = {0.f, 0.f, 0.125f, 0.375f};

  float gm1 = 1.f - g;
  float* orow = out + ((size_t)(b * C_ + c) * Hh) * Ww;
#pragma unroll
  for (int i = 0; i < 4; ++i) {
    int R = 4 * ty + i;
    float4 xv = *reinterpret_cast<const float4*>(&xpad[(R + 3) * 72 + 4 + 4 * tx]);
    float xvv[4] = {xv.x, xv.y, xv.z, xv.w};
    float ov[4];
#pragma unroll
    for (int j = 0; j < 4; ++j) {
      float sv = viA[i] * hA[j] + viB[i] * hB[j] + viC[i] * hC[j];
      ov[j] = xvv[j] + g * sv + gm1 * (acc[i][j] + bias);
    }
    *reinterpret_cast<float4*>(&orow[R * 64 + 4 * tx]) =
        make_float4(ov[0], ov[1], ov[2], ov[3]);
  }
}

// ---------------------------------------------------------------------------
extern "C" void kernel_launch(void* const* d_in, const int* in_sizes, int n_in,
                              void* d_out, int out_size, void* d_ws, size_t ws_size,
                              hipStream_t stream)
{
  const float* x    = (const float*)d_in[0];
  const float* inw  = (const float*)d_in[1];
  const float* xw   = (const float*)d_in[2];
  const float* dtw  = (const float*)d_in[3];
  const float* dtb  = (const float*)d_in[4];
  const float* cw   = (const float*)d_in[5];
  const float* cb   = (const float*)d_in[6];
  const float* alog = (const float*)d_in[7];
  const float* Dp   = (const float*)d_in[8];
  const float* ow   = (const float*)d_in[9];
  const float* nsw  = (const float*)d_in[10];
  const float* nsb  = (const float*)d_in[11];
  const float* n1w  = (const float*)d_in[12];
  const float* n1b  = (const float*)d_in[13];
  const float* dww  = (const float*)d_in[14];
  const float* dwb  = (const float*)d_in[15];
  const float* gate = (const float*)d_in[16];

  char* ws = (char*)d_ws;
  float* xln   = (float*)ws; ws += (size_t)8192 * 192 * 4;   // 6.3 MB
  float* xz    = (float*)ws; ws += (size_t)8192 * 768 * 4;   // 25.2 MB
  float* xc    = (float*)ws; ws += (size_t)8192 * 384 * 4;   // 12.6 MB
  float* delta = (float*)ws; ws += (size_t)8192 * 384 * 4;   // 12.6 MB
  float* BC    = (float*)ws; ws += (size_t)8192 * 32 * 4;    // 1.05 MB
  float* yg    = (float*)ws; ws += (size_t)8192 * 384 * 4;   // 12.6 MB
  float* yn  = xz;    // alias: xz dead after k_scan
  float* ssm = xln;   // alias: xln dead after gemm1

  k_pool_ln<<<B_ * 16, 256, 0, stream>>>(x, n1w, n1b, xln);
  k_gemm_f32<<<dim3(6, 64), 256, 0, stream>>>(xln, inw, xz, 768, 192);
  k_conv_silu<<<12288, 256, 0, stream>>>(xz, cw, cb, xc);
  k_xproj<<<2048, 256, 0, stream>>>(xc, xw, dtw, dtb, BC, delta);
  k_scan<<<B_ * 24, 256, 0, stream>>>(delta, xc, BC, xz, alog, Dp, yg);
  k_ln_ssm<<<8192, 128, 0, stream>>>(yg, nsw, nsb, yn);
  k_gemm_f32<<<dim3(2, 64), 256, 0, stream>>>(yn, ow, ssm, 192, 384);
  k_final<<<B_ * C_, 256, 0, stream>>>(x, dww, dwb, ssm, gate, (float*)d_out);
}